// Round 2
// baseline (659.510 us; speedup 1.0000x reference)
//
#include <hip/hip_runtime.h>
#include <cstdint>
#include <cstddef>

// ---------------- types ----------------
typedef __attribute__((ext_vector_type(8))) _Float16 half8;   // MFMA f16 A/B frag (4 VGPRs)
typedef __attribute__((ext_vector_type(4))) _Float16 half4;
typedef __attribute__((ext_vector_type(4))) float    floatx4; // MFMA C/D frag

static constexpr int B_ROWS = 16384;
static constexpr int IN_DIM = 256;
static constexpr int H_DIM  = 512;
static constexpr int NB     = 16;

__device__ __forceinline__ float fast_tanh(float x) {
  float ax = fabsf(x);
  float e  = __expf(2.0f * ax);             // e >= 1, inf-safe: 2/(inf+1) -> 0 -> t=1
  float t  = 1.0f - 2.0f / (e + 1.0f);
  return copysignf(t, x);
}

// ---------------- coeffs fp32 -> fp16 ----------------
__global__ __launch_bounds__(256) void cvt_f16_k(const float* __restrict__ src,
                                                 _Float16* __restrict__ dst,
                                                 size_t n4) {
  for (size_t i = (size_t)blockIdx.x * 256 + threadIdx.x; i < n4;
       i += (size_t)gridDim.x * 256) {
    float4 v = ((const float4*)src)[i];
    half4 r;
    r[0] = (_Float16)v.x; r[1] = (_Float16)v.y;
    r[2] = (_Float16)v.z; r[3] = (_Float16)v.w;
    ((half4*)dst)[i] = r;
  }
}

// ---------------- per-column stats, two-pass (deterministic, no atomics) ----------------
__global__ __launch_bounds__(256) void stats_part_k(const float* __restrict__ X,
                                                    int rows, int cols,
                                                    double* __restrict__ ps,
                                                    double* __restrict__ ps2) {
  // grid: (cols/64, SEGS); block 256 = 64 cols x 4 row-chunks (coalesced 64-float rows)
  int c     = blockIdx.x * 64 + (threadIdx.x & 63);
  int chunk = threadIdx.x >> 6;
  int seg   = blockIdx.y;
  int rps   = rows / gridDim.y;
  int r0    = seg * rps;
  double s = 0.0, s2 = 0.0;
  for (int r = r0 + chunk; r < r0 + rps; r += 4) {
    float v = X[(size_t)r * cols + c];
    s += v; s2 += (double)v * (double)v;
  }
  __shared__ double Ls[256], Ls2[256];
  Ls[threadIdx.x] = s; Ls2[threadIdx.x] = s2;
  __syncthreads();
  if (chunk == 0) {
    int cl = threadIdx.x;
    s  = Ls[cl]  + Ls[cl + 64]  + Ls[cl + 128]  + Ls[cl + 192];
    s2 = Ls2[cl] + Ls2[cl + 64] + Ls2[cl + 128] + Ls2[cl + 192];
    ps [(size_t)seg * cols + c] = s;
    ps2[(size_t)seg * cols + c] = s2;
  }
}

__global__ void stats_final_k(const double* __restrict__ ps,
                              const double* __restrict__ ps2,
                              int segs, int cols, int rows,
                              float* __restrict__ mu, float* __restrict__ isd) {
  int c = blockIdx.x * blockDim.x + threadIdx.x;
  if (c >= cols) return;
  double s = 0.0, s2 = 0.0;
  for (int g = 0; g < segs; g++) { s += ps[(size_t)g * cols + c]; s2 += ps2[(size_t)g * cols + c]; }
  double mean = s / rows;
  double var  = (s2 - s * s / rows) / (rows - 1);   // ddof=1 (torch-style unbiased)
  if (var < 0.0) var = 0.0;
  float sd = (float)sqrt(var);
  mu[c]  = (float)mean;
  isd[c] = 1.0f / (sd + 1e-6f);
}

// ---------------- normalize + clip to [-3,3] ----------------
__global__ __launch_bounds__(256) void normalize_k(const float* __restrict__ In,
                                                   float* __restrict__ Out,
                                                   const float* __restrict__ mu,
                                                   const float* __restrict__ isd,
                                                   size_t n4, int colmask) {
  for (size_t i = (size_t)blockIdx.x * 256 + threadIdx.x; i < n4;
       i += (size_t)gridDim.x * 256) {
    float4 v = ((const float4*)In)[i];
    int c = (int)((i << 2) & (size_t)colmask);   // cols is a power of 2
    v.x = fminf(fmaxf((v.x - mu[c + 0]) * isd[c + 0], -3.f), 3.f);
    v.y = fminf(fmaxf((v.y - mu[c + 1]) * isd[c + 1], -3.f), 3.f);
    v.z = fminf(fmaxf((v.z - mu[c + 2]) * isd[c + 2], -3.f), 3.f);
    v.w = fminf(fmaxf((v.w - mu[c + 3]) * isd[c + 3], -3.f), 3.f);
    ((float4*)Out)[i] = v;
  }
}

// ---------------- fused KAN GEMM: C[b,o] = sum_k basis(xn[b, k/16], k%16) * Cb[o,k] ----------------
// m97-style 128x128 tile, 4 waves (2x2), each wave 64x64 = 4x4 mfma_f32_16x16x32_f16 tiles.
// A-tile is generated on the fly from xn via the RBF recurrence (2 exps per xn).
__global__ __launch_bounds__(256) void kan_gemm_k(const float* __restrict__ XN,
                                                  const _Float16* __restrict__ Cb,
                                                  float* __restrict__ Hout,
                                                  int IN, int N, int act) {
  const int K = IN << 4;
  __shared__ __align__(16) _Float16 As[128 * 40];   // +8 pad breaks pow2 bank stride
  __shared__ __align__(16) _Float16 Bs[128 * 40];
  const int tid  = threadIdx.x;
  const int row0 = blockIdx.y * 128, col0 = blockIdx.x * 128;
  const int w = tid >> 6, lane = tid & 63;
  const int wm = w & 1, wn = w >> 1;
  const int lrow = lane & 15, quad = lane >> 4;

  // per-thread one-time basis constants K_n = exp(-2 c_n^2)
  float Kn[NB];
#pragma unroll
  for (int n = 0; n < NB; n++) {
    float c = -2.f + (float)n * (4.f / 15.f);
    Kn[n] = __expf(-2.f * c * c);
  }

  floatx4 acc[4][4] = {};

  const int s_row = tid >> 1, s_ii = tid & 1;
  const float* xrow = XN + (size_t)(row0 + s_row) * IN + s_ii;
  const _Float16* brow = Cb + (size_t)(col0 + s_row) * K + s_ii * 16;
  _Float16* aw = &As[s_row * 40 + s_ii * 16];
  _Float16* bw = &Bs[s_row * 40 + s_ii * 16];

  for (int k0 = 0; k0 < K; k0 += 32) {
    // issue B global loads early (latency hiding over the exp work)
    half8 g0 = *(const half8*)(brow + k0);
    half8 g1 = *(const half8*)(brow + k0 + 8);
    float xn  = xrow[k0 >> 4];
    // basis_n = W * g^n * K_n ; W = e^{-2x^2-8x}, g = e^{(16/15)x}
    float Wf = __expf(-2.f * xn * xn - 8.f * xn);
    float gf = __expf((16.f / 15.f) * xn);
    float p  = Wf;
    half8 h0, h1;
#pragma unroll
    for (int n = 0; n < 8; n++) { h0[n] = (_Float16)(p * Kn[n]);     p *= gf; }
#pragma unroll
    for (int n = 0; n < 8; n++) { h1[n] = (_Float16)(p * Kn[n + 8]); p *= gf; }
    *(half8*)aw       = h0;
    *(half8*)(aw + 8) = h1;
    *(half8*)bw       = g0;
    *(half8*)(bw + 8) = g1;
    __syncthreads();

    half8 af[4], bf4[4];
#pragma unroll
    for (int t4 = 0; t4 < 4; t4++) {
      af[t4]  = *(const half8*)&As[(wm * 64 + t4 * 16 + lrow) * 40 + quad * 8];
      bf4[t4] = *(const half8*)&Bs[(wn * 64 + t4 * 16 + lrow) * 40 + quad * 8];
    }
#pragma unroll
    for (int tm = 0; tm < 4; tm++)
#pragma unroll
      for (int tn = 0; tn < 4; tn++)
        acc[tm][tn] = __builtin_amdgcn_mfma_f32_16x16x32_f16(af[tm], bf4[tn], acc[tm][tn], 0, 0, 0);
    __syncthreads();
  }

  // epilogue: C/D layout col=lane&15, row=quad*4+reg (m89/m91-verified, dtype-independent)
#pragma unroll
  for (int tm = 0; tm < 4; tm++) {
#pragma unroll
    for (int tn = 0; tn < 4; tn++) {
      int gcol = col0 + wn * 64 + tn * 16 + lrow;
#pragma unroll
      for (int r = 0; r < 4; r++) {
        int grow = row0 + wm * 64 + tm * 16 + quad * 4 + r;
        float v = acc[tm][tn][r];
        if (act) v = fast_tanh(v);
        Hout[(size_t)grow * N + gcol] = v;
      }
    }
  }
}

// ---------------- layer 3 (out dim 1) + skip, fp32 ----------------
// block = 4 waves; each wave owns 4 rows; lane j covers i = lane + 64*j
__global__ __launch_bounds__(256) void layer3_k(const float* __restrict__ XN3,
                                                const float* __restrict__ C3,
                                                const float* __restrict__ X,
                                                const float* __restrict__ SW,
                                                const float* __restrict__ SB,
                                                float* __restrict__ OUT) {
  int w = threadIdx.x >> 6, lane = threadIdx.x & 63;
  float Kn[NB];
#pragma unroll
  for (int n = 0; n < NB; n++) {
    float c = -2.f + (float)n * (4.f / 15.f);
    Kn[n] = __expf(-2.f * c * c);
  }
  float sb0 = SB[0];
  int row_base = blockIdx.x * 16 + w * 4;
  for (int r = 0; r < 4; r++) {
    int row = row_base + r;
    float s = 0.f;
#pragma unroll
    for (int j = 0; j < 8; j++) {
      int i = lane + 64 * j;
      float xn = XN3[(size_t)row * H_DIM + i];
      float Wf = __expf(-2.f * xn * xn - 8.f * xn);
      float gf = __expf((16.f / 15.f) * xn);
      const floatx4* cp = (const floatx4*)(C3 + (size_t)i * NB);
      floatx4 c0 = cp[0], c1 = cp[1], c2 = cp[2], c3 = cp[3];
      float p = Wf;
#pragma unroll
      for (int n = 0; n < 4; n++) { s += p * Kn[n]      * c0[n]; p *= gf; }
#pragma unroll
      for (int n = 0; n < 4; n++) { s += p * Kn[n + 4]  * c1[n]; p *= gf; }
#pragma unroll
      for (int n = 0; n < 4; n++) { s += p * Kn[n + 8]  * c2[n]; p *= gf; }
#pragma unroll
      for (int n = 0; n < 4; n++) { s += p * Kn[n + 12] * c3[n]; p *= gf; }
    }
#pragma unroll
    for (int j = 0; j < 4; j++) {
      int i = lane + 64 * j;
      s += X[(size_t)row * IN_DIM + i] * SW[i];
    }
#pragma unroll
    for (int off = 32; off > 0; off >>= 1) s += __shfl_down(s, off);
    if (lane == 0) OUT[row] = s + sb0;
  }
}

// ---------------- launcher ----------------
extern "C" void kernel_launch(void* const* d_in, const int* in_sizes, int n_in,
                              void* d_out, int out_size, void* d_ws, size_t ws_size,
                              hipStream_t stream) {
  const float* x  = (const float*)d_in[0];   // [16384, 256]
  const float* c1 = (const float*)d_in[1];   // [512, 256, 16]
  const float* c2 = (const float*)d_in[2];   // [512, 512, 16]
  const float* c3 = (const float*)d_in[3];   // [1, 512, 16]
  const float* sw = (const float*)d_in[4];   // [1, 256]
  const float* sb = (const float*)d_in[5];   // [1]
  float* out = (float*)d_out;

  const int B = B_ROWS, IN = IN_DIM, H = H_DIM;

  char* ws = (char*)d_ws;
  size_t off = 0;
  auto alloc = [&](size_t bytes) -> void* {
    void* p = ws + off;
    off += (bytes + 255) & ~(size_t)255;
    return p;
  };
  _Float16* C1h = (_Float16*)alloc((size_t)H * IN * NB * 2);  //  4 MB
  _Float16* C2h = (_Float16*)alloc((size_t)H * H  * NB * 2);  //  8 MB
  float* H1 = (float*)alloc((size_t)B * H * 4);               // 32 MB
  float* H2 = (float*)alloc((size_t)B * H * 4);               // 32 MB
  double* ps  = (double*)alloc(32 * 512 * 8);
  double* ps2 = (double*)alloc(32 * 512 * 8);
  float* mu  = (float*)alloc(512 * 4);
  float* isd = (float*)alloc(512 * 4);
  float* XN1 = H2;  // alias: XN1 dead before GEMM2 writes H2

  // coeff conversion
  cvt_f16_k<<<1024, 256, 0, stream>>>(c1, C1h, (size_t)H * IN * NB / 4);
  cvt_f16_k<<<1024, 256, 0, stream>>>(c2, C2h, (size_t)H * H  * NB / 4);

  // ---- layer 1 ----
  stats_part_k<<<dim3(IN / 64, 32), 256, 0, stream>>>(x, B, IN, ps, ps2);
  stats_final_k<<<1, 256, 0, stream>>>(ps, ps2, 32, IN, B, mu, isd);
  normalize_k<<<1024, 256, 0, stream>>>(x, XN1, mu, isd, (size_t)B * IN / 4, IN - 1);
  kan_gemm_k<<<dim3(H / 128, B / 128), 256, 0, stream>>>(XN1, C1h, H1, IN, H, 1);

  // ---- layer 2 ----
  stats_part_k<<<dim3(H / 64, 32), 256, 0, stream>>>(H1, B, H, ps, ps2);
  stats_final_k<<<2, 256, 0, stream>>>(ps, ps2, 32, H, B, mu, isd);
  normalize_k<<<2048, 256, 0, stream>>>(H1, H1, mu, isd, (size_t)B * H / 4, H - 1);
  kan_gemm_k<<<dim3(H / 128, B / 128), 256, 0, stream>>>(H1, C2h, H2, H, H, 1);

  // ---- layer 3 + skip ----
  stats_part_k<<<dim3(H / 64, 32), 256, 0, stream>>>(H2, B, H, ps, ps2);
  stats_final_k<<<2, 256, 0, stream>>>(ps, ps2, 32, H, B, mu, isd);
  normalize_k<<<2048, 256, 0, stream>>>(H2, H2, mu, isd, (size_t)B * H / 4, H - 1);
  layer3_k<<<B / 16, 256, 0, stream>>>(H2, c3, x, sw, sb, out);
}